// Round 23
// baseline (2816.144 us; speedup 1.0000x reference)
//
#include <hip/hip_runtime.h>

// Net_46076409152296: spiking net fwd (RLeaky+Leaky). B=1024,T=32,D=2312,H=512,O=10.
// v23: K1 BK 16 (slabs 145 vs 193 -> fewer barrier drains, the measured
// overlap-inefficiency term), balanced operand mix kept from v22 (Xs f64 /
// Ws f32: VALU 288 = LDS 288 cyc per 64-fma window). LDS = exactly 64KB;
// 2 blocks/CU residency preserved (128KB <= 160KB pool). W prefetch moved
// LATE (post-compute) to hold live regs <= the 128-VGPR / 2-waves cliff.
// Math bit-identical (ascending-k f64 fma, exact cvt). K0/K2/launcher verbatim.

constexpr int Bq = 1024, Tq = 32, Dq = 2312, Hq = 512, Oq = 10;

// ---------------- K0: WrTf[k][j] = Wr[j][k]  (f32 coalesced transpose)
__global__ __launch_bounds__(256) void snn_wrt(
    const float* __restrict__ Wr, float* __restrict__ WrTf) {
  __shared__ float t[32][33];
  const int bx = blockIdx.x;
  const int by = blockIdx.y;
  const int lx = threadIdx.x & 31, ly = threadIdx.x >> 5;
#pragma unroll
  for (int i = 0; i < 4; ++i)
    t[ly + 8 * i][lx] = Wr[(size_t)(by * 32 + ly + 8 * i) * Hq + bx * 32 + lx];
  __syncthreads();
#pragma unroll
  for (int i = 0; i < 4; ++i)
    WrTf[(size_t)(bx * 32 + ly + 8 * i) * Hq + by * 32 + lx] = t[lx][ly + 8 * i];
}

// ---------------- K1: C[m][n] = f64dot(x[m,:], W1[n,:]) + b1[n]
// 128x128 tile, 256 thr, 8x8 f64 micro, BK=16 (+8 tail).
// Xs f64: chunk c at [kk][c*10..+7]; Ws f32: chunk c at [kk][c*12..+7].
__global__ __launch_bounds__(256) void snn_fc1_gemm(
    const float* __restrict__ x, const float* __restrict__ W1,
    const float* __restrict__ b1, float* __restrict__ cur1) {
  __shared__ double Xs[2][16][160];  // 40.96 KB
  __shared__ float  Ws[2][16][192];  // 24.58 KB   (total = 65536 B exactly)

  const int tid = threadIdx.x;
  const int tx = tid & 15;
  const int ty = tid >> 4;
  const size_t m0 = (size_t)blockIdx.y * 128;
  const int n0 = blockIdx.x * 128;
  const int srow = tid >> 1;              // 0..127
  const int kc8 = (tid & 1) * 8;          // main slabs (width 16)
  const int kc4 = (tid & 1) * 4;          // tail slab (width 8)
  const int schX = (srow >> 3) * 10 + (srow & 7);   // f64 tile position
  const int schW = (srow >> 3) * 12 + (srow & 7);   // f32 tile position
  const float* __restrict__ ax = x + (m0 + srow) * Dq;
  const float* __restrict__ bx = W1 + (size_t)(n0 + srow) * Dq;

  double acc[8][8];
#pragma unroll
  for (int i = 0; i < 8; ++i)
#pragma unroll
    for (int j = 0; j < 8; ++j) acc[i][j] = 0.0;

  // prologue: stage slab 0 (k 0..15)
  {
    const float4 xa = *(const float4*)(ax + kc8);
    const float4 xb = *(const float4*)(ax + kc8 + 4);
    const float4 wa = *(const float4*)(bx + kc8);
    const float4 wb = *(const float4*)(bx + kc8 + 4);
    Xs[0][kc8 + 0][schX] = (double)xa.x;
    Xs[0][kc8 + 1][schX] = (double)xa.y;
    Xs[0][kc8 + 2][schX] = (double)xa.z;
    Xs[0][kc8 + 3][schX] = (double)xa.w;
    Xs[0][kc8 + 4][schX] = (double)xb.x;
    Xs[0][kc8 + 5][schX] = (double)xb.y;
    Xs[0][kc8 + 6][schX] = (double)xb.z;
    Xs[0][kc8 + 7][schX] = (double)xb.w;
    Ws[0][kc8 + 0][schW] = wa.x;
    Ws[0][kc8 + 1][schW] = wa.y;
    Ws[0][kc8 + 2][schW] = wa.z;
    Ws[0][kc8 + 3][schW] = wa.w;
    Ws[0][kc8 + 4][schW] = wb.x;
    Ws[0][kc8 + 5][schW] = wb.y;
    Ws[0][kc8 + 6][schW] = wb.z;
    Ws[0][kc8 + 7][schW] = wb.w;
  }
  __syncthreads();

#define FRAG_STEP(BUF, KK)                                               \
  do {                                                                   \
    double a[8];                                                         \
    *(double2*)&a[0] = *(const double2*)&Xs[BUF][KK][ty * 10 + 0];       \
    *(double2*)&a[2] = *(const double2*)&Xs[BUF][KK][ty * 10 + 2];       \
    *(double2*)&a[4] = *(const double2*)&Xs[BUF][KK][ty * 10 + 4];       \
    *(double2*)&a[6] = *(const double2*)&Xs[BUF][KK][ty * 10 + 6];       \
    float bf[8];                                                         \
    *(float4*)&bf[0] = *(const float4*)&Ws[BUF][KK][tx * 12 + 0];        \
    *(float4*)&bf[4] = *(const float4*)&Ws[BUF][KK][tx * 12 + 4];        \
    double bd[8];                                                        \
    _Pragma("unroll") for (int i = 0; i < 8; ++i) bd[i] = (double)bf[i]; \
    _Pragma("unroll") for (int i = 0; i < 8; ++i)                        \
        _Pragma("unroll") for (int j = 0; j < 8; ++j)                    \
            acc[i][j] = fma(a[i], bd[j], acc[i][j]);                     \
  } while (0)

  // 145 slabs: s=0..143 width 16, s=144 width 8 (k = 2304..2311)
  for (int s = 0; s < 145; ++s) {
    const int buf = s & 1;
    float4 xa, xb;
    const bool hasNext = (s + 1 < 145);
    const bool nextFull = (s + 1 < 144);
    if (hasNext) {  // early-issue X prefetch only (keeps live regs low)
      const int nk = (s + 1) * 16;
      if (nextFull) {
        xa = *(const float4*)(ax + nk + kc8);
        xb = *(const float4*)(ax + nk + kc8 + 4);
      } else {
        xa = *(const float4*)(ax + 2304 + kc4);
      }
    }
    if (s < 144) {
#pragma unroll
      for (int kk = 0; kk < 16; ++kk) FRAG_STEP(buf, kk);
    } else {
#pragma unroll
      for (int kk = 0; kk < 8; ++kk) FRAG_STEP(buf, kk);
    }
    if (hasNext) {
      const int nb = buf ^ 1;
      if (nextFull) {
        const int nk = (s + 1) * 16;
        const float4 wa = *(const float4*)(bx + nk + kc8);      // late W load
        const float4 wb = *(const float4*)(bx + nk + kc8 + 4);
        Xs[nb][kc8 + 0][schX] = (double)xa.x;
        Xs[nb][kc8 + 1][schX] = (double)xa.y;
        Xs[nb][kc8 + 2][schX] = (double)xa.z;
        Xs[nb][kc8 + 3][schX] = (double)xa.w;
        Xs[nb][kc8 + 4][schX] = (double)xb.x;
        Xs[nb][kc8 + 5][schX] = (double)xb.y;
        Xs[nb][kc8 + 6][schX] = (double)xb.z;
        Xs[nb][kc8 + 7][schX] = (double)xb.w;
        Ws[nb][kc8 + 0][schW] = wa.x;
        Ws[nb][kc8 + 1][schW] = wa.y;
        Ws[nb][kc8 + 2][schW] = wa.z;
        Ws[nb][kc8 + 3][schW] = wa.w;
        Ws[nb][kc8 + 4][schW] = wb.x;
        Ws[nb][kc8 + 5][schW] = wb.y;
        Ws[nb][kc8 + 6][schW] = wb.z;
        Ws[nb][kc8 + 7][schW] = wb.w;
      } else {
        const float4 wa = *(const float4*)(bx + 2304 + kc4);
        Xs[nb][kc4 + 0][schX] = (double)xa.x;
        Xs[nb][kc4 + 1][schX] = (double)xa.y;
        Xs[nb][kc4 + 2][schX] = (double)xa.z;
        Xs[nb][kc4 + 3][schX] = (double)xa.w;
        Ws[nb][kc4 + 0][schW] = wa.x;
        Ws[nb][kc4 + 1][schW] = wa.y;
        Ws[nb][kc4 + 2][schW] = wa.z;
        Ws[nb][kc4 + 3][schW] = wa.w;
      }
      __syncthreads();
    }
  }
#undef FRAG_STEP

  float bl[8];
  *(float4*)&bl[0] = *(const float4*)(b1 + n0 + tx * 8);
  *(float4*)&bl[4] = *(const float4*)(b1 + n0 + tx * 8 + 4);
#pragma unroll
  for (int i = 0; i < 8; ++i) {
    float* crow = cur1 + (m0 + ty * 8 + i) * Hq + n0 + tx * 8;
    float4 v0, v1;
    v0.x = __fadd_rn((float)acc[i][0], bl[0]);
    v0.y = __fadd_rn((float)acc[i][1], bl[1]);
    v0.z = __fadd_rn((float)acc[i][2], bl[2]);
    v0.w = __fadd_rn((float)acc[i][3], bl[3]);
    v1.x = __fadd_rn((float)acc[i][4], bl[4]);
    v1.y = __fadd_rn((float)acc[i][5], bl[5]);
    v1.z = __fadd_rn((float)acc[i][6], bl[6]);
    v1.w = __fadd_rn((float)acc[i][7], bl[7]);
    *(float4*)(crow) = v0;
    *(float4*)(crow + 4) = v1;
  }
}

// ---------------- K2 helpers: pipelined sparse gather (WrT f32; cvt exact)
__device__ __forceinline__ void gather8(const unsigned short* __restrict__ row,
                                        int base, int j,
                                        const float* __restrict__ WrTf,
                                        double* g) {
  const uint4 pk = *(const uint4*)&row[base];
  const int k0 = pk.x & 0xffff, k1 = pk.x >> 16;
  const int k2 = pk.y & 0xffff, k3 = pk.y >> 16;
  const int k4 = pk.z & 0xffff, k5 = pk.z >> 16;
  const int k6 = pk.w & 0xffff, k7 = pk.w >> 16;
  g[0] = (double)WrTf[(size_t)k0 * Hq + j];
  g[1] = (double)WrTf[(size_t)k1 * Hq + j];
  g[2] = (double)WrTf[(size_t)k2 * Hq + j];
  g[3] = (double)WrTf[(size_t)k3 * Hq + j];
  g[4] = (double)WrTf[(size_t)k4 * Hq + j];
  g[5] = (double)WrTf[(size_t)k5 * Hq + j];
  g[6] = (double)WrTf[(size_t)k6 * Hq + j];
  g[7] = (double)WrTf[(size_t)k7 * Hq + j];
}
__device__ __forceinline__ void acc8(const double* g, int rem, double& rA,
                                     double& rB, double& rC, double& rD) {
  if (rem >= 8) {
    rA += g[0]; rB += g[1]; rC += g[2]; rD += g[3];
    rA += g[4]; rB += g[5]; rC += g[6]; rD += g[7];
  } else {
    if (rem > 0) rA += g[0];
    if (rem > 1) rB += g[1];
    if (rem > 2) rC += g[2];
    if (rem > 3) rD += g[3];
    if (rem > 4) rA += g[4];
    if (rem > 5) rB += g[5];
    if (rem > 6) rC += g[6];
  }
}

// ---------------- K2: sparse-spike recurrent scan (v19 verbatim)
__global__ __launch_bounds__(512) void snn_scan(
    const float* __restrict__ cur1, const float* __restrict__ WrTf,
    const float* __restrict__ br, const float* __restrict__ W2,
    const float* __restrict__ b2, float* __restrict__ out, int b_off) {
  __shared__ float spkF[4][512];
  __shared__ unsigned short idxL[4][512];
  __shared__ unsigned long long masksL[4][8];
  __shared__ int cnts[4];

  const int j = threadIdx.x;
  const int wv = j >> 6;
  const int lane = j & 63;
  const int lb = blockIdx.x * 4;
  const int gb = b_off + lb;

  float m1[4] = {0.f, 0.f, 0.f, 0.f};
  float m2 = 0.f;
#pragma unroll
  for (int r = 0; r < 4; ++r) { spkF[r][j] = 0.f; idxL[r][j] = 0; }
  if (j < 4) cnts[j] = 0;
  __syncthreads();

  const float brr = br[j];

  const int g = j >> 3, l = j & 7;
  const int r2g = g / 10, o2 = g - r2g * 10;
  const bool doB = (j < 320);
  const float b2v = doB ? b2[o2] : 0.f;
  const float* __restrict__ w2p = doB ? (W2 + (size_t)o2 * Hq) : W2;

  for (int t = 0; t < Tq; ++t) {
    float c1[4];
#pragma unroll
    for (int r = 0; r < 4; ++r)
      c1[r] = cur1[((size_t)(lb + r) * Tq + t) * Hq + j];

    double rec[4];
#pragma unroll
    for (int r = 0; r < 4; ++r) {
      const int cnt = cnts[r];
      double rA = 0.0, rB = 0.0, rC = 0.0, rD = 0.0;
      double g0[8], g1[8];
      if (cnt > 0) gather8(&idxL[r][0], 0, j, WrTf, g0);
      for (int i0 = 0; i0 < cnt; i0 += 16) {
        if (i0 + 8 < cnt) gather8(&idxL[r][0], i0 + 8, j, WrTf, g1);
        acc8(g0, cnt - i0, rA, rB, rC, rD);
        if (i0 + 16 < cnt) gather8(&idxL[r][0], i0 + 16, j, WrTf, g0);
        if (i0 + 8 < cnt) acc8(g1, cnt - (i0 + 8), rA, rB, rC, rD);
      }
      rec[r] = (rA + rB) + (rC + rD);
    }
    __syncthreads();

    unsigned long long bm[4];
    int bits = 0;
#pragma unroll
    for (int r = 0; r < 4; ++r) {
      const float rst = (m1[r] - 1.0f > 0.0f) ? 1.0f : 0.0f;
      const float mn = __fsub_rn(
          __fadd_rn(__fadd_rn(__fmul_rn(0.99f, m1[r]), c1[r]),
                    __fadd_rn((float)rec[r], brr)),
          rst);
      m1[r] = mn;
      const bool bit = (mn - 1.0f > 0.0f);
      spkF[r][j] = bit ? 1.0f : 0.0f;
      if (bit) bits |= (1 << r);
      bm[r] = __ballot(bit);
      if (lane == 0) masksL[r][wv] = bm[r];
    }
    __syncthreads();

#pragma unroll
    for (int r = 0; r < 4; ++r) {
      int base = 0;
#pragma unroll
      for (int w = 0; w < 8; ++w)
        if (w < wv) base += __popcll(masksL[r][w]);
      if (bits & (1 << r)) {
        const int pos = base + __popcll(bm[r] & ((1ull << lane) - 1ull));
        idxL[r][pos] = (unsigned short)j;
      }
    }
    if (j < 4) {
      int c = 0;
#pragma unroll
      for (int w = 0; w < 8; ++w) c += __popcll(masksL[j][w]);
      cnts[j] = c;
    }
    if (doB) {
      double p = 0.0;
#pragma unroll
      for (int s8 = 0; s8 < 64; ++s8) {
        const int k = l + (s8 << 3);
        p = fma((double)spkF[r2g][k], (double)w2p[k], p);
      }
      p += __shfl_down(p, 4, 8);
      p += __shfl_down(p, 2, 8);
      p += __shfl_down(p, 1, 8);
      if (l == 0) {
        const float cur2 = __fadd_rn((float)p, b2v);
        const float rst2 = (m2 - 1.0f > 0.0f) ? 1.0f : 0.0f;
        const float mn2 =
            __fsub_rn(__fadd_rn(__fmul_rn(0.99f, m2), cur2), rst2);
        m2 = mn2;
        const size_t oidx = ((size_t)t * Bq + (gb + r2g)) * Oq + o2;
        out[oidx] = (mn2 - 1.0f > 0.0f) ? 1.0f : 0.0f;
        out[(size_t)Tq * Bq * Oq + oidx] = mn2;
      }
    }
    __syncthreads();
  }
}

extern "C" void kernel_launch(void* const* d_in, const int* in_sizes, int n_in,
                              void* d_out, int out_size, void* d_ws, size_t ws_size,
                              hipStream_t stream) {
  const float* x  = (const float*)d_in[0];
  const float* W1 = (const float*)d_in[1];
  const float* b1 = (const float*)d_in[2];
  const float* Wr = (const float*)d_in[3];
  const float* br = (const float*)d_in[4];
  const float* W2 = (const float*)d_in[5];
  const float* b2 = (const float*)d_in[6];
  float* out = (float*)d_out;  // FP32
  (void)in_sizes; (void)n_in; (void)out_size;

  float* WrTf = (float*)d_ws;                        // 1 MB
  float* cur1 = (float*)d_ws + Hq * Hq;              // after WrTf
  const size_t avail = ws_size - (size_t)Hq * Hq * sizeof(float);

  snn_wrt<<<dim3(16, 16), 256, 0, stream>>>(Wr, WrTf);

  int nb = Bq;
  while (nb > 4 && (size_t)nb * Tq * Hq * sizeof(float) > avail) nb >>= 1;

  for (int b_off = 0; b_off < Bq; b_off += nb) {
    snn_fc1_gemm<<<dim3(Hq / 128, nb * Tq / 128), 256, 0, stream>>>(
        x + (size_t)b_off * Tq * Dq, W1, b1, cur1);
    snn_scan<<<nb / 4, 512, 0, stream>>>(cur1, WrTf, br, W2, b2, out, b_off);
  }
}

// Round 24
// 2266.980 us; speedup vs baseline: 1.2422x; 1.2422x over previous
//
#include <hip/hip_runtime.h>

// Net_46076409152296: spiking net fwd (RLeaky+Leaky). B=1024,T=32,D=2312,H=512,O=10.
// v24 = v22 verbatim (best measured: 2.24 ms total; K1 1.75 ms @ VGPR 128,
// 2 waves/SIMD). v23's BK=16 pushed VGPR to 176 -> occupancy cliff -> revert.
// Structure: K1 mixed LDS (Xs f64 stride-10 pad / Ws f32 stride-12 pad, BK=12,
// balanced VALU/LDS pipes); K2 sparse-spike scan (ballot compaction + f32 WrT
// gathers); K0 transpose. All dots f64 ascending-k (bit-stable across rounds);
// fp32 state updates in reference order. absmax 0.1054688 (data-inherent).

constexpr int Bq = 1024, Tq = 32, Dq = 2312, Hq = 512, Oq = 10;

// ---------------- K0: WrTf[k][j] = Wr[j][k]  (f32 coalesced transpose)
__global__ __launch_bounds__(256) void snn_wrt(
    const float* __restrict__ Wr, float* __restrict__ WrTf) {
  __shared__ float t[32][33];
  const int bx = blockIdx.x;
  const int by = blockIdx.y;
  const int lx = threadIdx.x & 31, ly = threadIdx.x >> 5;
#pragma unroll
  for (int i = 0; i < 4; ++i)
    t[ly + 8 * i][lx] = Wr[(size_t)(by * 32 + ly + 8 * i) * Hq + bx * 32 + lx];
  __syncthreads();
#pragma unroll
  for (int i = 0; i < 4; ++i)
    WrTf[(size_t)(bx * 32 + ly + 8 * i) * Hq + by * 32 + lx] = t[lx][ly + 8 * i];
}

// ---------------- K1: C[m][n] = f64dot(x[m,:], W1[n,:]) + b1[n]
// 128x128 tile, 256 thr, 8x8 f64 micro, BK=12 (+8 tail).
// Xs f64: chunk c at [kk][c*10 .. c*10+7]; Ws f32: chunk c at [kk][c*12 .. +7].
__global__ __launch_bounds__(256) void snn_fc1_gemm(
    const float* __restrict__ x, const float* __restrict__ W1,
    const float* __restrict__ b1, float* __restrict__ cur1) {
  __shared__ double Xs[2][12][160];  // 30.7 KB
  __shared__ float  Ws[2][12][192];  // 18.4 KB

  const int tid = threadIdx.x;
  const int tx = tid & 15;
  const int ty = tid >> 4;
  const size_t m0 = (size_t)blockIdx.y * 128;
  const int n0 = blockIdx.x * 128;
  const int srow = tid >> 1;              // 0..127
  const int kc6 = (tid & 1) * 6;          // main slabs (width 12)
  const int kc4 = (tid & 1) * 4;          // tail slab (width 8)
  const int schX = (srow >> 3) * 10 + (srow & 7);   // f64 tile position
  const int schW = (srow >> 3) * 12 + (srow & 7);   // f32 tile position
  const float* __restrict__ ax = x + (m0 + srow) * Dq;
  const float* __restrict__ bx = W1 + (size_t)(n0 + srow) * Dq;

  double acc[8][8];
#pragma unroll
  for (int i = 0; i < 8; ++i)
#pragma unroll
    for (int j = 0; j < 8; ++j) acc[i][j] = 0.0;

  // prologue: stage slab 0 (k 0..11)
  {
    const float4 a4 = *(const float4*)(ax + kc6);
    const float2 a2 = *(const float2*)(ax + kc6 + 4);
    const float4 b4 = *(const float4*)(bx + kc6);
    const float2 b2 = *(const float2*)(bx + kc6 + 4);
    Xs[0][kc6 + 0][schX] = (double)a4.x;
    Xs[0][kc6 + 1][schX] = (double)a4.y;
    Xs[0][kc6 + 2][schX] = (double)a4.z;
    Xs[0][kc6 + 3][schX] = (double)a4.w;
    Xs[0][kc6 + 4][schX] = (double)a2.x;
    Xs[0][kc6 + 5][schX] = (double)a2.y;
    Ws[0][kc6 + 0][schW] = b4.x;
    Ws[0][kc6 + 1][schW] = b4.y;
    Ws[0][kc6 + 2][schW] = b4.z;
    Ws[0][kc6 + 3][schW] = b4.w;
    Ws[0][kc6 + 4][schW] = b2.x;
    Ws[0][kc6 + 5][schW] = b2.y;
  }
  __syncthreads();

#define FRAG_STEP(BUF, KK)                                               \
  do {                                                                   \
    double a[8];                                                         \
    *(double2*)&a[0] = *(const double2*)&Xs[BUF][KK][ty * 10 + 0];       \
    *(double2*)&a[2] = *(const double2*)&Xs[BUF][KK][ty * 10 + 2];       \
    *(double2*)&a[4] = *(const double2*)&Xs[BUF][KK][ty * 10 + 4];       \
    *(double2*)&a[6] = *(const double2*)&Xs[BUF][KK][ty * 10 + 6];       \
    float bf[8];                                                         \
    *(float4*)&bf[0] = *(const float4*)&Ws[BUF][KK][tx * 12 + 0];        \
    *(float4*)&bf[4] = *(const float4*)&Ws[BUF][KK][tx * 12 + 4];        \
    double bd[8];                                                        \
    _Pragma("unroll") for (int i = 0; i < 8; ++i) bd[i] = (double)bf[i]; \
    _Pragma("unroll") for (int i = 0; i < 8; ++i)                        \
        _Pragma("unroll") for (int j = 0; j < 8; ++j)                    \
            acc[i][j] = fma(a[i], bd[j], acc[i][j]);                     \
  } while (0)

  // 193 slabs: s=0..191 width 12, s=192 width 8 (k = 2304..2311)
  for (int s = 0; s < 193; ++s) {
    const int buf = s & 1;
    float4 a4, b4;
    float2 a2, b2;
    const bool hasNext = (s + 1 < 193);
    const bool nextFull = (s + 1 < 192);
    if (hasNext) {
      const int nk = (s + 1) * 12;
      if (nextFull) {
        a4 = *(const float4*)(ax + nk + kc6);
        a2 = *(const float2*)(ax + nk + kc6 + 4);
        b4 = *(const float4*)(bx + nk + kc6);
        b2 = *(const float2*)(bx + nk + kc6 + 4);
      } else {
        a4 = *(const float4*)(ax + 2304 + kc4);
        b4 = *(const float4*)(bx + 2304 + kc4);
      }
    }
    if (s < 192) {
#pragma unroll
      for (int kk = 0; kk < 12; ++kk) FRAG_STEP(buf, kk);
    } else {
#pragma unroll
      for (int kk = 0; kk < 8; ++kk) FRAG_STEP(buf, kk);
    }
    if (hasNext) {
      const int nb = buf ^ 1;
      if (nextFull) {
        Xs[nb][kc6 + 0][schX] = (double)a4.x;
        Xs[nb][kc6 + 1][schX] = (double)a4.y;
        Xs[nb][kc6 + 2][schX] = (double)a4.z;
        Xs[nb][kc6 + 3][schX] = (double)a4.w;
        Xs[nb][kc6 + 4][schX] = (double)a2.x;
        Xs[nb][kc6 + 5][schX] = (double)a2.y;
        Ws[nb][kc6 + 0][schW] = b4.x;
        Ws[nb][kc6 + 1][schW] = b4.y;
        Ws[nb][kc6 + 2][schW] = b4.z;
        Ws[nb][kc6 + 3][schW] = b4.w;
        Ws[nb][kc6 + 4][schW] = b2.x;
        Ws[nb][kc6 + 5][schW] = b2.y;
      } else {
        Xs[nb][kc4 + 0][schX] = (double)a4.x;
        Xs[nb][kc4 + 1][schX] = (double)a4.y;
        Xs[nb][kc4 + 2][schX] = (double)a4.z;
        Xs[nb][kc4 + 3][schX] = (double)a4.w;
        Ws[nb][kc4 + 0][schW] = b4.x;
        Ws[nb][kc4 + 1][schW] = b4.y;
        Ws[nb][kc4 + 2][schW] = b4.z;
        Ws[nb][kc4 + 3][schW] = b4.w;
      }
      __syncthreads();
    }
  }
#undef FRAG_STEP

  float bl[8];
  *(float4*)&bl[0] = *(const float4*)(b1 + n0 + tx * 8);
  *(float4*)&bl[4] = *(const float4*)(b1 + n0 + tx * 8 + 4);
#pragma unroll
  for (int i = 0; i < 8; ++i) {
    float* crow = cur1 + (m0 + ty * 8 + i) * Hq + n0 + tx * 8;
    float4 v0, v1;
    v0.x = __fadd_rn((float)acc[i][0], bl[0]);
    v0.y = __fadd_rn((float)acc[i][1], bl[1]);
    v0.z = __fadd_rn((float)acc[i][2], bl[2]);
    v0.w = __fadd_rn((float)acc[i][3], bl[3]);
    v1.x = __fadd_rn((float)acc[i][4], bl[4]);
    v1.y = __fadd_rn((float)acc[i][5], bl[5]);
    v1.z = __fadd_rn((float)acc[i][6], bl[6]);
    v1.w = __fadd_rn((float)acc[i][7], bl[7]);
    *(float4*)(crow) = v0;
    *(float4*)(crow + 4) = v1;
  }
}

// ---------------- K2 helpers: pipelined sparse gather (WrT f32; cvt exact)
__device__ __forceinline__ void gather8(const unsigned short* __restrict__ row,
                                        int base, int j,
                                        const float* __restrict__ WrTf,
                                        double* g) {
  const uint4 pk = *(const uint4*)&row[base];
  const int k0 = pk.x & 0xffff, k1 = pk.x >> 16;
  const int k2 = pk.y & 0xffff, k3 = pk.y >> 16;
  const int k4 = pk.z & 0xffff, k5 = pk.z >> 16;
  const int k6 = pk.w & 0xffff, k7 = pk.w >> 16;
  g[0] = (double)WrTf[(size_t)k0 * Hq + j];
  g[1] = (double)WrTf[(size_t)k1 * Hq + j];
  g[2] = (double)WrTf[(size_t)k2 * Hq + j];
  g[3] = (double)WrTf[(size_t)k3 * Hq + j];
  g[4] = (double)WrTf[(size_t)k4 * Hq + j];
  g[5] = (double)WrTf[(size_t)k5 * Hq + j];
  g[6] = (double)WrTf[(size_t)k6 * Hq + j];
  g[7] = (double)WrTf[(size_t)k7 * Hq + j];
}
__device__ __forceinline__ void acc8(const double* g, int rem, double& rA,
                                     double& rB, double& rC, double& rD) {
  if (rem >= 8) {
    rA += g[0]; rB += g[1]; rC += g[2]; rD += g[3];
    rA += g[4]; rB += g[5]; rC += g[6]; rD += g[7];
  } else {
    if (rem > 0) rA += g[0];
    if (rem > 1) rB += g[1];
    if (rem > 2) rC += g[2];
    if (rem > 3) rD += g[3];
    if (rem > 4) rA += g[4];
    if (rem > 5) rB += g[5];
    if (rem > 6) rC += g[6];
  }
}

// ---------------- K2: sparse-spike recurrent scan
__global__ __launch_bounds__(512) void snn_scan(
    const float* __restrict__ cur1, const float* __restrict__ WrTf,
    const float* __restrict__ br, const float* __restrict__ W2,
    const float* __restrict__ b2, float* __restrict__ out, int b_off) {
  __shared__ float spkF[4][512];
  __shared__ unsigned short idxL[4][512];
  __shared__ unsigned long long masksL[4][8];
  __shared__ int cnts[4];

  const int j = threadIdx.x;
  const int wv = j >> 6;
  const int lane = j & 63;
  const int lb = blockIdx.x * 4;
  const int gb = b_off + lb;

  float m1[4] = {0.f, 0.f, 0.f, 0.f};
  float m2 = 0.f;
#pragma unroll
  for (int r = 0; r < 4; ++r) { spkF[r][j] = 0.f; idxL[r][j] = 0; }
  if (j < 4) cnts[j] = 0;
  __syncthreads();

  const float brr = br[j];

  const int g = j >> 3, l = j & 7;
  const int r2g = g / 10, o2 = g - r2g * 10;
  const bool doB = (j < 320);
  const float b2v = doB ? b2[o2] : 0.f;
  const float* __restrict__ w2p = doB ? (W2 + (size_t)o2 * Hq) : W2;

  for (int t = 0; t < Tq; ++t) {
    float c1[4];
#pragma unroll
    for (int r = 0; r < 4; ++r)
      c1[r] = cur1[((size_t)(lb + r) * Tq + t) * Hq + j];

    double rec[4];
#pragma unroll
    for (int r = 0; r < 4; ++r) {
      const int cnt = cnts[r];
      double rA = 0.0, rB = 0.0, rC = 0.0, rD = 0.0;
      double g0[8], g1[8];
      if (cnt > 0) gather8(&idxL[r][0], 0, j, WrTf, g0);
      for (int i0 = 0; i0 < cnt; i0 += 16) {
        if (i0 + 8 < cnt) gather8(&idxL[r][0], i0 + 8, j, WrTf, g1);
        acc8(g0, cnt - i0, rA, rB, rC, rD);
        if (i0 + 16 < cnt) gather8(&idxL[r][0], i0 + 16, j, WrTf, g0);
        if (i0 + 8 < cnt) acc8(g1, cnt - (i0 + 8), rA, rB, rC, rD);
      }
      rec[r] = (rA + rB) + (rC + rD);
    }
    __syncthreads();

    unsigned long long bm[4];
    int bits = 0;
#pragma unroll
    for (int r = 0; r < 4; ++r) {
      const float rst = (m1[r] - 1.0f > 0.0f) ? 1.0f : 0.0f;
      const float mn = __fsub_rn(
          __fadd_rn(__fadd_rn(__fmul_rn(0.99f, m1[r]), c1[r]),
                    __fadd_rn((float)rec[r], brr)),
          rst);
      m1[r] = mn;
      const bool bit = (mn - 1.0f > 0.0f);
      spkF[r][j] = bit ? 1.0f : 0.0f;
      if (bit) bits |= (1 << r);
      bm[r] = __ballot(bit);
      if (lane == 0) masksL[r][wv] = bm[r];
    }
    __syncthreads();

#pragma unroll
    for (int r = 0; r < 4; ++r) {
      int base = 0;
#pragma unroll
      for (int w = 0; w < 8; ++w)
        if (w < wv) base += __popcll(masksL[r][w]);
      if (bits & (1 << r)) {
        const int pos = base + __popcll(bm[r] & ((1ull << lane) - 1ull));
        idxL[r][pos] = (unsigned short)j;
      }
    }
    if (j < 4) {
      int c = 0;
#pragma unroll
      for (int w = 0; w < 8; ++w) c += __popcll(masksL[j][w]);
      cnts[j] = c;
    }
    if (doB) {
      double p = 0.0;
#pragma unroll
      for (int s8 = 0; s8 < 64; ++s8) {
        const int k = l + (s8 << 3);
        p = fma((double)spkF[r2g][k], (double)w2p[k], p);
      }
      p += __shfl_down(p, 4, 8);
      p += __shfl_down(p, 2, 8);
      p += __shfl_down(p, 1, 8);
      if (l == 0) {
        const float cur2 = __fadd_rn((float)p, b2v);
        const float rst2 = (m2 - 1.0f > 0.0f) ? 1.0f : 0.0f;
        const float mn2 =
            __fsub_rn(__fadd_rn(__fmul_rn(0.99f, m2), cur2), rst2);
        m2 = mn2;
        const size_t oidx = ((size_t)t * Bq + (gb + r2g)) * Oq + o2;
        out[oidx] = (mn2 - 1.0f > 0.0f) ? 1.0f : 0.0f;
        out[(size_t)Tq * Bq * Oq + oidx] = mn2;
      }
    }
    __syncthreads();
  }
}

extern "C" void kernel_launch(void* const* d_in, const int* in_sizes, int n_in,
                              void* d_out, int out_size, void* d_ws, size_t ws_size,
                              hipStream_t stream) {
  const float* x  = (const float*)d_in[0];
  const float* W1 = (const float*)d_in[1];
  const float* b1 = (const float*)d_in[2];
  const float* Wr = (const float*)d_in[3];
  const float* br = (const float*)d_in[4];
  const float* W2 = (const float*)d_in[5];
  const float* b2 = (const float*)d_in[6];
  float* out = (float*)d_out;  // FP32
  (void)in_sizes; (void)n_in; (void)out_size;

  float* WrTf = (float*)d_ws;                        // 1 MB
  float* cur1 = (float*)d_ws + Hq * Hq;              // after WrTf
  const size_t avail = ws_size - (size_t)Hq * Hq * sizeof(float);

  snn_wrt<<<dim3(16, 16), 256, 0, stream>>>(Wr, WrTf);

  int nb = Bq;
  while (nb > 4 && (size_t)nb * Tq * Hq * sizeof(float) > avail) nb >>= 1;

  for (int b_off = 0; b_off < Bq; b_off += nb) {
    snn_fc1_gemm<<<dim3(Hq / 128, nb * Tq / 128), 256, 0, stream>>>(
        x + (size_t)b_off * Tq * Dq, W1, b1, cur1);
    snn_scan<<<nb / 4, 512, 0, stream>>>(cur1, WrTf, br, W2, b2, out, b_off);
  }
}